// Round 11
// baseline (167.501 us; speedup 1.0000x reference)
//
#include <hip/hip_runtime.h>
#include <hip/hip_bf16.h>

#define BATCH  16384
#define FDIM   256
#define EDIM   128
#define KN     32
#define NNODES 100000
#define REPS   4

typedef __bf16 bf16x8 __attribute__((ext_vector_type(8)));
typedef float  f32x4  __attribute__((ext_vector_type(4)));

__device__ __forceinline__ unsigned short f2bf(float x) {
    return __builtin_bit_cast(unsigned short, (__bf16)x);
}
__device__ __forceinline__ float bflo(unsigned v) {
    return __builtin_bit_cast(float, v << 16);
}
__device__ __forceinline__ float bfhi(unsigned v) {
    return __builtin_bit_cast(float, v & 0xffff0000u);
}

// ---------- ws layout ----------
#define PB_BYTES     ((size_t)NNODES * 256)
#define SBATCH_BYTES ((size_t)BATCH * 256)
#define WH_BYTES     ((size_t)2 * 128 * 256)
#define NEW_WS       (PB_BYTES + SBATCH_BYTES + 2 * WH_BYTES)
#define DIAG_WS      (NEW_WS + PB_BYTES + 65536)

// ---------------- conv: W[512][128] f32 -> wbtS + wbtP ----------------
__global__ void conv_w6(const float* __restrict__ weight,
                        char* __restrict__ wbtS, char* __restrict__ wbtP)
{
    const int gid  = blockIdx.x * 256 + threadIdx.x;
    const int head = gid >> 12;
    const int H    = (gid >> 11) & 1;
    const int j    = (gid >> 4) & 127;
    const int g    = gid & 15;
    union { unsigned short u[8]; uint4 v; } p;
    #pragma unroll
    for (int e = 0; e < 8; ++e) {
        const int k = H * 128 + g * 8 + e;
        p.u[e] = f2bf(weight[(size_t)(k + head * 256) * EDIM + j]);
    }
    char* dst = head ? wbtP : wbtS;
    *(uint4*)(dst + (size_t)H * 32768 + j * 256 + ((g * 16) ^ ((j & 7) << 4))) = p.v;
}

// ---------------- proj7 (unchanged from round 10) ----------------
__global__ __launch_bounds__(256, 2)
void proj7(const float* __restrict__ feat, const char* __restrict__ wbt,
           char* __restrict__ Pb)
{
    __shared__ __align__(16) char ldsA[64 * 512];
    __shared__ __align__(16) char ldsB[32768];

    const int t    = threadIdx.x;
    const int lane = t & 63;
    const int w    = t >> 6;
    const int q    = lane >> 4;
    const int p    = lane & 15;
    const int m0   = blockIdx.x * 64;

    #pragma unroll
    for (int i = 0; i < 8; ++i) {
        const int g = i * 256 + t;
        __builtin_amdgcn_global_load_lds((const void*)(wbt + g * 16),
                                         (void*)(ldsB + g * 16), 16, 0, 0);
    }
    #pragma unroll
    for (int batch = 0; batch < 2; ++batch) {
        float4 v[8];
        #pragma unroll
        for (int jj = 0; jj < 8; ++jj) {
            int row = m0 + w * 16 + batch * 8 + jj;
            if (row > NNODES - 1) row = NNODES - 1;
            v[jj] = ((const float4*)(feat + (size_t)row * FDIM))[lane];
        }
        #pragma unroll
        for (int jj = 0; jj < 8; ++jj) {
            const int r = w * 16 + batch * 8 + jj;
            union { unsigned short u[4]; uint2 x; } pk;
            pk.u[0] = f2bf(v[jj].x); pk.u[1] = f2bf(v[jj].y);
            pk.u[2] = f2bf(v[jj].z); pk.u[3] = f2bf(v[jj].w);
            *(uint2*)(ldsA + r * 512 + ((lane * 8) ^ ((r & 7) << 4))) = pk.x;
        }
    }

    f32x4 acc[8];
    #pragma unroll
    for (int n = 0; n < 8; ++n) acc[n] = (f32x4){0.f, 0.f, 0.f, 0.f};

#define PCOMPUTE(H)                                                          \
    do {                                                                     \
        _Pragma("unroll")                                                    \
        for (int kt = 0; kt < 4; ++kt) {                                     \
            const int ar = w * 16 + p;                                       \
            const bf16x8 a = *(const bf16x8*)(ldsA + ar * 512 +              \
                (((H) * 256 + kt * 64 + q * 16) ^ ((ar & 7) << 4)));         \
            _Pragma("unroll")                                                \
            for (int n = 0; n < 8; ++n) {                                    \
                const int j = n * 16 + p;                                    \
                const bf16x8 b = *(const bf16x8*)(ldsB + j * 256 +           \
                    ((kt * 64 + q * 16) ^ ((j & 7) << 4)));                  \
                acc[n] = __builtin_amdgcn_mfma_f32_16x16x32_bf16(            \
                    a, b, acc[n], 0, 0, 0);                                  \
            }                                                                \
        }                                                                    \
    } while (0)

    __syncthreads();
    PCOMPUTE(0);
    __syncthreads();
    #pragma unroll
    for (int i = 0; i < 8; ++i) {
        const int g = i * 256 + t;
        __builtin_amdgcn_global_load_lds((const void*)(wbt + 32768 + g * 16),
                                         (void*)(ldsB + g * 16), 16, 0, 0);
    }
    __syncthreads();
    PCOMPUTE(1);
#undef PCOMPUTE

    #pragma unroll
    for (int n = 0; n < 8; ++n)
        #pragma unroll
        for (int jj = 0; jj < 4; ++jj) {
            const int row = m0 + w * 16 + q * 4 + jj;
            if (row < NNODES)
                *(unsigned short*)(Pb + (size_t)row * 256 + (n * 16 + p) * 2)
                    = f2bf(acc[n][jj]);
        }
}

// ---------------- selfg2 (unchanged) ----------------
__global__ __launch_bounds__(256, 1)
void selfg2(const int* __restrict__ nodes, const float* __restrict__ feat,
            const char* __restrict__ wbt, char* __restrict__ Sbatch)
{
    __shared__ __align__(16) char ldsA[64 * 1024];
    __shared__ __align__(16) char ldsB[32768];

    const int t    = threadIdx.x;
    const int lane = t & 63;
    const int w    = t >> 6;
    const int q    = lane >> 4;
    const int p    = lane & 15;
    const int m0   = blockIdx.x * 64;

    #pragma unroll
    for (int i = 0; i < 8; ++i) {
        const int g = i * 256 + t;
        __builtin_amdgcn_global_load_lds((const void*)(wbt + g * 16),
                                         (void*)(ldsB + g * 16), 16, 0, 0);
    }
    #pragma unroll
    for (int i = 0; i < 16; ++i) {
        const int g = i * 256 + t;
        const int r = g >> 6;
        const int x = (g & 63) * 16;
        const int nid = nodes[m0 + r];
        __builtin_amdgcn_global_load_lds(
            (const void*)((const char*)feat + (size_t)nid * 1024
                          + (x ^ ((r & 7) << 4))),
            (void*)(ldsA + (size_t)r * 1024 + x), 16, 0, 0);
    }

    f32x4 acc[8];
    #pragma unroll
    for (int n = 0; n < 8; ++n) acc[n] = (f32x4){0.f, 0.f, 0.f, 0.f};

#define SCOMPUTE(H)                                                          \
    do {                                                                     \
        _Pragma("unroll")                                                    \
        for (int kt = 0; kt < 4; ++kt) {                                     \
            const int ar = w * 16 + p;                                       \
            const int sw = (ar & 7) << 4;                                    \
            const f32x4 lo = *(const f32x4*)(ldsA + (size_t)ar * 1024 +      \
                (((H) * 512 + kt * 128 + q * 32) ^ sw));                     \
            const f32x4 hi = *(const f32x4*)(ldsA + (size_t)ar * 1024 +      \
                (((H) * 512 + kt * 128 + q * 32 + 16) ^ sw));                \
            bf16x8 a;                                                        \
            a[0] = (__bf16)lo[0]; a[1] = (__bf16)lo[1];                      \
            a[2] = (__bf16)lo[2]; a[3] = (__bf16)lo[3];                      \
            a[4] = (__bf16)hi[0]; a[5] = (__bf16)hi[1];                      \
            a[6] = (__bf16)hi[2]; a[7] = (__bf16)hi[3];                      \
            _Pragma("unroll")                                                \
            for (int n = 0; n < 8; ++n) {                                    \
                const int j = n * 16 + p;                                    \
                const bf16x8 b = *(const bf16x8*)(ldsB + j * 256 +           \
                    ((kt * 64 + q * 16) ^ ((j & 7) << 4)));                  \
                acc[n] = __builtin_amdgcn_mfma_f32_16x16x32_bf16(            \
                    a, b, acc[n], 0, 0, 0);                                  \
            }                                                                \
        }                                                                    \
    } while (0)

    __syncthreads();
    SCOMPUTE(0);
    __syncthreads();
    #pragma unroll
    for (int i = 0; i < 8; ++i) {
        const int g = i * 256 + t;
        __builtin_amdgcn_global_load_lds((const void*)(wbt + 32768 + g * 16),
                                         (void*)(ldsB + g * 16), 16, 0, 0);
    }
    __syncthreads();
    SCOMPUTE(1);
#undef SCOMPUTE

    #pragma unroll
    for (int n = 0; n < 8; ++n)
        #pragma unroll
        for (int jj = 0; jj < 4; ++jj) {
            const int row = m0 + w * 16 + q * 4 + jj;
            *(unsigned short*)(Sbatch + (size_t)row * 256 + (n * 16 + p) * 2)
                = f2bf(acc[n][jj]);
        }
}

// ---------------- gather3 (unchanged) ----------------
__global__ __launch_bounds__(256, 4)
void gather3(const int* __restrict__ neigh, const char* __restrict__ Sbatch,
             const char* __restrict__ Pb, float* __restrict__ out)
{
    const int lane = threadIdx.x & 63;
    const int b    = __builtin_amdgcn_readfirstlane(blockIdx.x * 4 + (threadIdx.x >> 6));

    const unsigned sv = *(const unsigned*)(Sbatch + (size_t)b * 256 + lane * 4);

    const int* nb = neigh + (size_t)b * KN;
    float a0 = 0.f, a1 = 0.f;
    #pragma unroll
    for (int k = 0; k < KN; k += 8) {
        int id[8];
        #pragma unroll
        for (int j = 0; j < 8; ++j)
            id[j] = __builtin_amdgcn_readfirstlane(nb[k + j]);
        unsigned v[8];
        #pragma unroll
        for (int j = 0; j < 8; ++j)
            v[j] = *(const unsigned*)(Pb + (size_t)id[j] * 256 + lane * 4);
        #pragma unroll
        for (int j = 0; j < 8; ++j) {
            a0 += bflo(v[j]);
            a1 += bfhi(v[j]);
        }
    }

    const float inv = 1.0f / 32.0f;
    float o0 = bflo(sv) + a0 * inv;
    float o1 = bfhi(sv) + a1 * inv;
    o0 = o0 > 0.f ? o0 : 0.f;
    o1 = o1 > 0.f ? o1 : 0.f;
    ((float2*)out)[(size_t)b * 64 + lane] = make_float2(o0, o1);
}

// ================= DIAGNOSTIC KERNELS (write scratch only) =================
// Same grid (1563), 256 thr, launch_bounds(256,2), 64 KB LDS footprint as proj7.

__global__ __launch_bounds__(256, 2)
void diagA(const float* __restrict__ feat, float* __restrict__ scr)
{
    __shared__ __align__(16) char ldsA[64 * 512];
    __shared__ __align__(16) char ldsB[32768];
    const int t    = threadIdx.x;
    const int lane = t & 63;
    const int w    = t >> 6;
    const int m0   = blockIdx.x * 64;
    ((volatile int*)ldsB)[t] = t;   // anchor ldsB allocation

    for (int rep = 0; rep < REPS; ++rep) {
        asm volatile("" ::: "memory");
        #pragma unroll
        for (int batch = 0; batch < 2; ++batch) {
            float4 v[8];
            #pragma unroll
            for (int jj = 0; jj < 8; ++jj) {
                int row = m0 + w * 16 + batch * 8 + jj;
                if (row > NNODES - 1) row = NNODES - 1;
                v[jj] = ((const float4*)(feat + (size_t)row * FDIM))[lane];
            }
            #pragma unroll
            for (int jj = 0; jj < 8; ++jj) {
                const int r = w * 16 + batch * 8 + jj;
                union { unsigned short u[4]; uint2 x; } pk;
                pk.u[0] = f2bf(v[jj].x); pk.u[1] = f2bf(v[jj].y);
                pk.u[2] = f2bf(v[jj].z); pk.u[3] = f2bf(v[jj].w);
                *(uint2*)(ldsA + r * 512 + ((lane * 8) ^ ((r & 7) << 4))) = pk.x;
            }
        }
        __syncthreads();
    }
    float kv = *(const float*)(ldsA + (t & 2047) * 8);
    asm volatile("" :: "v"(kv));
    if (kv == 123456789.0f) scr[blockIdx.x] = kv;
}

__global__ __launch_bounds__(256, 2)
void diagB(const char* __restrict__ wbt, float* __restrict__ scr)
{
    __shared__ __align__(16) char ldsA[64 * 512];
    __shared__ __align__(16) char ldsB[32768];
    const int t = threadIdx.x;
    ((volatile int*)ldsA)[t] = t;   // anchor ldsA allocation

    for (int rep = 0; rep < REPS; ++rep) {
        asm volatile("" ::: "memory");
        #pragma unroll
        for (int half = 0; half < 2; ++half) {
            #pragma unroll
            for (int i = 0; i < 8; ++i) {
                const int g = i * 256 + t;
                __builtin_amdgcn_global_load_lds(
                    (const void*)(wbt + half * 32768 + g * 16),
                    (void*)(ldsB + g * 16), 16, 0, 0);
            }
            __syncthreads();
        }
    }
    float kv = *(const float*)(ldsB + (t & 8191) * 4);
    asm volatile("" :: "v"(kv));
    if (kv == 123456789.0f) scr[blockIdx.x] = kv;
}

__global__ __launch_bounds__(256, 2)
void diagAB(const float* __restrict__ feat, const char* __restrict__ wbt,
            float* __restrict__ scr)
{
    __shared__ __align__(16) char ldsA[64 * 512];
    __shared__ __align__(16) char ldsB[32768];
    const int t    = threadIdx.x;
    const int lane = t & 63;
    const int w    = t >> 6;
    const int m0   = blockIdx.x * 64;

    for (int rep = 0; rep < REPS; ++rep) {
        asm volatile("" ::: "memory");
        #pragma unroll
        for (int i = 0; i < 8; ++i) {
            const int g = i * 256 + t;
            __builtin_amdgcn_global_load_lds((const void*)(wbt + g * 16),
                                             (void*)(ldsB + g * 16), 16, 0, 0);
        }
        #pragma unroll
        for (int batch = 0; batch < 2; ++batch) {
            float4 v[8];
            #pragma unroll
            for (int jj = 0; jj < 8; ++jj) {
                int row = m0 + w * 16 + batch * 8 + jj;
                if (row > NNODES - 1) row = NNODES - 1;
                v[jj] = ((const float4*)(feat + (size_t)row * FDIM))[lane];
            }
            #pragma unroll
            for (int jj = 0; jj < 8; ++jj) {
                const int r = w * 16 + batch * 8 + jj;
                union { unsigned short u[4]; uint2 x; } pk;
                pk.u[0] = f2bf(v[jj].x); pk.u[1] = f2bf(v[jj].y);
                pk.u[2] = f2bf(v[jj].z); pk.u[3] = f2bf(v[jj].w);
                *(uint2*)(ldsA + r * 512 + ((lane * 8) ^ ((r & 7) << 4))) = pk.x;
            }
        }
        __syncthreads();
        #pragma unroll
        for (int i = 0; i < 8; ++i) {
            const int g = i * 256 + t;
            __builtin_amdgcn_global_load_lds((const void*)(wbt + 32768 + g * 16),
                                             (void*)(ldsB + g * 16), 16, 0, 0);
        }
        __syncthreads();
    }
    float kv = *(const float*)(ldsA + (t & 2047) * 8)
             + *(const float*)(ldsB + (t & 8191) * 4);
    asm volatile("" :: "v"(kv));
    if (kv == 123456789.0f) scr[blockIdx.x] = kv;
}

__global__ __launch_bounds__(256, 2)
void diagS(char* __restrict__ scrPb, float* __restrict__ scr)
{
    __shared__ __align__(16) char ldsA[64 * 512];
    __shared__ __align__(16) char ldsB[32768];
    const int t    = threadIdx.x;
    const int lane = t & 63;
    const int w    = t >> 6;
    const int q    = lane >> 4;
    const int p    = lane & 15;
    const int m0   = blockIdx.x * 64;
    ((volatile int*)ldsA)[t] = t;
    ((volatile int*)ldsB)[t] = t;

    const float base = (float)(t * 3 + 1);
    for (int rep = 0; rep < REPS; ++rep) {
        asm volatile("" ::: "memory");
        #pragma unroll
        for (int n = 0; n < 8; ++n)
            #pragma unroll
            for (int jj = 0; jj < 4; ++jj) {
                const int row = m0 + w * 16 + q * 4 + jj;
                if (row < NNODES)
                    *(unsigned short*)(scrPb + (size_t)row * 256 + (n * 16 + p) * 2)
                        = f2bf(base + n * 4 + jj + rep);
            }
    }
    asm volatile("" ::: "memory");
    if (base == -1.0f) scr[blockIdx.x] = base;
}

// ================= fallback path (round-2): cat + gemm =================
#define CAT_BYTES ((size_t)BATCH * 1024)
#define WB_BYTES  ((size_t)512 * EDIM * 2)

__global__ void conv_w(const float* __restrict__ weight, char* __restrict__ wb)
{
    const int t  = blockIdx.x * 256 + threadIdx.x;
    const int c  = t & 127;
    const int g  = (t >> 7) & 15;
    const int kt = t >> 11;
    union { unsigned short u[8]; uint4 v; } p;
    #pragma unroll
    for (int j = 0; j < 8; ++j)
        p.u[j] = f2bf(weight[(size_t)(kt * 128 + g * 8 + j) * EDIM + c]);
    *(uint4*)(wb + (size_t)kt * 32768 + c * 256 + ((g * 16) ^ ((c & 7) << 4))) = p.v;
}

__global__ __launch_bounds__(256, 4)
void gather_agg(const int* __restrict__ nodes, const int* __restrict__ neigh,
                const float* __restrict__ feat, char* __restrict__ cat)
{
    const int lane = threadIdx.x & 63;
    const int row  = __builtin_amdgcn_readfirstlane(blockIdx.x * 4 + (threadIdx.x >> 6));
    const int s    = (row & 7) << 4;
    const int nid  = __builtin_amdgcn_readfirstlane(nodes[row]);
    float4 sf = ((const float4*)(feat + (size_t)nid * FDIM))[lane];
    const int* nb = neigh + (size_t)row * KN;
    float ax = 0.f, ay = 0.f, az = 0.f, aw = 0.f;
    #pragma unroll
    for (int k = 0; k < KN; k += 8) {
        int id[8];
        #pragma unroll
        for (int j = 0; j < 8; ++j) id[j] = __builtin_amdgcn_readfirstlane(nb[k + j]);
        float4 v[8];
        #pragma unroll
        for (int j = 0; j < 8; ++j) v[j] = ((const float4*)(feat + (size_t)id[j] * FDIM))[lane];
        #pragma unroll
        for (int j = 0; j < 8; ++j) { ax += v[j].x; ay += v[j].y; az += v[j].z; aw += v[j].w; }
    }
    char* rowp = cat + (size_t)row * 1024;
    {
        union { unsigned short u[4]; uint2 v; } p;
        p.u[0] = f2bf(sf.x); p.u[1] = f2bf(sf.y); p.u[2] = f2bf(sf.z); p.u[3] = f2bf(sf.w);
        *(uint2*)(rowp + ((lane * 8) ^ s)) = p.v;
    }
    {
        const float inv = 1.0f / 32.0f;
        union { unsigned short u[4]; uint2 v; } p;
        p.u[0] = f2bf(ax * inv); p.u[1] = f2bf(ay * inv);
        p.u[2] = f2bf(az * inv); p.u[3] = f2bf(aw * inv);
        *(uint2*)(rowp + ((512 + lane * 8) ^ s)) = p.v;
    }
}

__global__ __launch_bounds__(256, 2)
void gemm_out(const char* __restrict__ cat, const char* __restrict__ wb,
              float* __restrict__ out)
{
    __shared__ __align__(16) char lds_a[64 * 256];
    __shared__ __align__(16) char lds_b[128 * 256];
    const int t    = threadIdx.x;
    const int lane = t & 63;
    const int w    = t >> 6;
    const int m0   = blockIdx.x * 64;
    const int r0   = w * 16;
    const int q    = lane >> 4;
    const int p    = lane & 15;
    const int ps   = (p & 7) << 4;
    f32x4 acc[8];
    #pragma unroll
    for (int n = 0; n < 8; ++n) acc[n] = (f32x4){0.f, 0.f, 0.f, 0.f};
    for (int kt = 0; kt < 4; ++kt) {
        #pragma unroll
        for (int i = 0; i < 4; ++i) {
            const int g   = i * 256 + t;
            const int row = g >> 4;
            const int x   = (g & 15) * 16;
            __builtin_amdgcn_global_load_lds(
                (const void*)(cat + (size_t)(m0 + row) * 1024 + kt * 256 + x),
                (void*)(lds_a + g * 16), 16, 0, 0);
        }
        #pragma unroll
        for (int i = 0; i < 8; ++i) {
            const int g = i * 256 + t;
            __builtin_amdgcn_global_load_lds(
                (const void*)(wb + (size_t)kt * 32768 + g * 16),
                (void*)(lds_b + g * 16), 16, 0, 0);
        }
        __syncthreads();
        #pragma unroll
        for (int kk = 0; kk < 4; ++kk) {
            const int xo = (kk * 64 + q * 16);
            bf16x8 a = *(const bf16x8*)(lds_a + (r0 + p) * 256 + (xo ^ ps));
            #pragma unroll
            for (int n = 0; n < 8; ++n) {
                bf16x8 b = *(const bf16x8*)(lds_b + (n * 16 + p) * 256 + (xo ^ ps));
                acc[n] = __builtin_amdgcn_mfma_f32_16x16x32_bf16(a, b, acc[n], 0, 0, 0);
            }
        }
        __syncthreads();
    }
    #pragma unroll
    for (int n = 0; n < 8; ++n) {
        #pragma unroll
        for (int j = 0; j < 4; ++j) {
            const float v = acc[n][j];
            out[(size_t)(m0 + r0 + q * 4 + j) * EDIM + n * 16 + p] = v > 0.f ? v : 0.f;
        }
    }
}

extern "C" void kernel_launch(void* const* d_in, const int* in_sizes, int n_in,
                              void* d_out, int out_size, void* d_ws, size_t ws_size,
                              hipStream_t stream) {
    const int*   nodes  = (const int*)d_in[0];
    const int*   neigh  = (const int*)d_in[1];
    const float* feat   = (const float*)d_in[2];
    const float* weight = (const float*)d_in[3];
    float*       out    = (float*)d_out;

    if (ws_size >= DIAG_WS) {
        char* Pb     = (char*)d_ws;
        char* Sbatch = (char*)d_ws + PB_BYTES;
        char* wbtS   = (char*)d_ws + PB_BYTES + SBATCH_BYTES;
        char* wbtP   = wbtS + WH_BYTES;
        char* scrPb  = (char*)d_ws + NEW_WS;
        float* scr   = (float*)((char*)d_ws + NEW_WS + PB_BYTES);

        conv_w6<<<32, 256, 0, stream>>>(weight, wbtS, wbtP);
        proj7<<<(NNODES + 63) / 64, 256, 0, stream>>>(feat, wbtP, Pb);
        selfg2<<<BATCH / 64, 256, 0, stream>>>(nodes, feat, wbtS, Sbatch);
        gather3<<<BATCH / 4, 256, 0, stream>>>(neigh, Sbatch, Pb, out);

        // diagnostics (scratch-only)
        const int g = (NNODES + 63) / 64;
        diagA <<<g, 256, 0, stream>>>(feat, scr);
        diagB <<<g, 256, 0, stream>>>(wbtP, scr);
        diagAB<<<g, 256, 0, stream>>>(feat, wbtP, scr);
        diagS <<<g, 256, 0, stream>>>(scrPb, scr);
    } else if (ws_size >= NEW_WS) {
        char* Pb     = (char*)d_ws;
        char* Sbatch = (char*)d_ws + PB_BYTES;
        char* wbtS   = (char*)d_ws + PB_BYTES + SBATCH_BYTES;
        char* wbtP   = wbtS + WH_BYTES;
        conv_w6<<<32, 256, 0, stream>>>(weight, wbtS, wbtP);
        proj7<<<(NNODES + 63) / 64, 256, 0, stream>>>(feat, wbtP, Pb);
        selfg2<<<BATCH / 64, 256, 0, stream>>>(nodes, feat, wbtS, Sbatch);
        gather3<<<BATCH / 4, 256, 0, stream>>>(neigh, Sbatch, Pb, out);
    } else {
        char* cat = (char*)d_ws;
        char* wb  = (char*)d_ws + CAT_BYTES;
        conv_w<<<32, 256, 0, stream>>>(weight, wb);
        gather_agg<<<BATCH / 4, 256, 0, stream>>>(nodes, neigh, feat, cat);
        gemm_out<<<BATCH / 64, 256, 0, stream>>>(cat, wb, out);
    }
}